// Round 5
// baseline (210.994 us; speedup 1.0000x reference)
//
#include <hip/hip_runtime.h>

#define B_  2
#define NX_ 512
#define NC_ 4096
#define D_  1024
#define H_  16
#define HD_ 64
#define NT_ (NX_ + NC_)   // 4608
#define NSPLIT 8
#define KBS (NT_ / 64 / NSPLIT)   // 9 key-blocks per split

typedef float  floatx4  __attribute__((ext_vector_type(4)));
typedef __bf16 bf16x8   __attribute__((ext_vector_type(8)));
typedef unsigned short ushort8v __attribute__((ext_vector_type(8)));

__device__ __forceinline__ bf16x8 as_bf16x8(ushort8v u) {
    union { ushort8v u; bf16x8 b; } c; c.u = u; return c.b;
}
// fp32 -> bf16 round-to-nearest-even
__device__ __forceinline__ unsigned short f2bf(float f) {
    unsigned u = __float_as_uint(f);
    u += 0x7FFF + ((u >> 16) & 1);
    return (unsigned short)(u >> 16);
}

// ================ prep: LN + tcast(Wq) + tcast(Wo) + pack_mask + cast(c) [+ fused kv0] + zero(gacc) ================
__global__ __launch_bounds__(256)
void prep_kernel(const float* __restrict__ x, const float* __restrict__ lw,
                 const float* __restrict__ lb, const float* __restrict__ Wq,
                 const float* __restrict__ Wo, const int* __restrict__ mask,
                 const float* __restrict__ c,
                 unsigned short* __restrict__ xnb, unsigned short* __restrict__ WqT,
                 unsigned short* __restrict__ WoT, unsigned* __restrict__ bits,
                 unsigned short* __restrict__ cbf, float* __restrict__ gz,
                 float* __restrict__ kv0o) {
    int blk = blockIdx.x;
    int tid = threadIdx.x;
    if (blk < 1024) {
        int row = blk;
        float4 v = reinterpret_cast<const float4*>(x)[(size_t)row * (D_ / 4) + tid];
        float s  = v.x + v.y + v.z + v.w;
        float s2 = v.x * v.x + v.y * v.y + v.z * v.z + v.w * v.w;
        #pragma unroll
        for (int off = 32; off > 0; off >>= 1) {
            s  += __shfl_down(s, off);
            s2 += __shfl_down(s2, off);
        }
        __shared__ float sm[4], sm2[4], stat[2];
        int wv = tid >> 6;
        if ((tid & 63) == 0) { sm[wv] = s; sm2[wv] = s2; }
        __syncthreads();
        if (tid == 0) {
            float S  = sm[0] + sm[1] + sm[2] + sm[3];
            float S2 = sm2[0] + sm2[1] + sm2[2] + sm2[3];
            float mu  = S * (1.0f / D_);
            float var = fmaxf(S2 * (1.0f / D_) - mu * mu, 0.0f);
            stat[0] = mu;
            stat[1] = rsqrtf(var + 1e-5f);
        }
        __syncthreads();
        float mu = stat[0], rs = stat[1];
        float4 w4 = reinterpret_cast<const float4*>(lw)[tid];
        float4 b4 = reinterpret_cast<const float4*>(lb)[tid];
        ushort4 o;
        o.x = f2bf((v.x - mu) * rs * w4.x + b4.x);
        o.y = f2bf((v.y - mu) * rs * w4.y + b4.y);
        o.z = f2bf((v.z - mu) * rs * w4.z + b4.z);
        o.w = f2bf((v.w - mu) * rs * w4.w + b4.w);
        reinterpret_cast<ushort4*>(xnb)[(size_t)row * (D_ / 4) + tid] = o;
    } else if (blk < 1536) {
        int which = (blk - 1024) >> 8;
        int t = (blk - 1024) & 255;
        const float* W = which ? Wo : Wq;
        unsigned short* WT = which ? WoT : WqT;
        __shared__ unsigned short T[64][72];
        int row0 = (t >> 4) * 64, col0 = (t & 15) * 64;
        int r = tid >> 2, ch = (tid & 3) * 16;
        const float* src = W + (size_t)(row0 + r) * D_ + col0 + ch;
        unsigned short vals[16];
        #pragma unroll
        for (int k = 0; k < 4; ++k) {
            float4 v = reinterpret_cast<const float4*>(src)[k];
            vals[k*4+0] = f2bf(v.x); vals[k*4+1] = f2bf(v.y);
            vals[k*4+2] = f2bf(v.z); vals[k*4+3] = f2bf(v.w);
        }
        #pragma unroll
        for (int i = 0; i < 16; ++i) T[ch + i][r] = vals[i];
        __syncthreads();
        unsigned short* dst = WT + (size_t)(col0 + r) * D_ + row0 + ch;
        uint4 o0 = *reinterpret_cast<uint4*>(&T[r][ch]);
        uint4 o1 = *reinterpret_cast<uint4*>(&T[r][ch + 8]);
        *reinterpret_cast<uint4*>(dst)     = o0;
        *reinterpret_cast<uint4*>(dst + 8) = o1;
    } else if (blk < 2048) {
        size_t w = (size_t)(blk - 1536) * 256 + tid;
        const int* src = mask + w * 32;
        unsigned b = 0;
        #pragma unroll
        for (int k = 0; k < 8; ++k) {
            int4 v = reinterpret_cast<const int4*>(src)[k];
            b |= (v.x != 0 ? 1u : 0u) << (k * 4 + 0);
            b |= (v.y != 0 ? 1u : 0u) << (k * 4 + 1);
            b |= (v.z != 0 ? 1u : 0u) << (k * 4 + 2);
            b |= (v.w != 0 ? 1u : 0u) << (k * 4 + 3);
        }
        bits[w] = b;
    } else if (blk < 10240) {
        size_t i = ((size_t)(blk - 2048) * 256 + tid) * 4;
        float4 v = *reinterpret_cast<const float4*>(c + i);
        ushort4 o;
        o.x = f2bf(v.x); o.y = f2bf(v.y); o.z = f2bf(v.z); o.w = f2bf(v.w);
        *reinterpret_cast<ushort4*>(cbf + i) = o;
        if (kv0o != nullptr) {
            // fused kv0: out2[b,h,n,d] = c[b,n,h*64+d]
            size_t row = i >> 10;            // b*NC_ + n
            int dd = (int)(i & 1023);
            int hh = dd >> 6, d4 = (dd & 63) >> 2;
            int bb = (int)(row >> 12);       // /NC_
            int n  = (int)(row & 4095);
            size_t o4 = (((size_t)(bb * 16 + hh) * NC_ + n) << 4) + d4;  // float4 index
            reinterpret_cast<float4*>(kv0o)[o4] = v;
        }
    } else {
        size_t i = ((size_t)(blk - 10240) * 256 + tid) * 4;
        float4 z = {0.f, 0.f, 0.f, 0.f};
        *reinterpret_cast<float4*>(gz + i) = z;
    }
}

// ---------------- kv0 fallback (only when d_ws too small): runs LAST ----------------
__global__ __launch_bounds__(256)
void kv0_kernel(const float* __restrict__ c, float* __restrict__ out2) {
    size_t i = (size_t)blockIdx.x * 256 + threadIdx.x;
    int d4 = (int)(i & 15);
    size_t r = i >> 4;
    int n = (int)(r % NC_);
    size_t r2 = r / NC_;
    int h = (int)(r2 & (H_ - 1));
    int b = (int)(r2 >> 4);
    float4 v = *reinterpret_cast<const float4*>(c + ((size_t)(b * NC_ + n)) * D_ + h * HD_ + d4 * 4);
    reinterpret_cast<float4*>(out2)[i] = v;
}

// ---------------- MFMA GEMM (q-proj): qbf = xnb @ Wq (B given as WqT); out bf16 ----------------
__global__ __launch_bounds__(256)
void gemm_bt_kernel(const unsigned short* __restrict__ A, const unsigned short* __restrict__ BT,
                    unsigned short* __restrict__ Cb) {
    __shared__ unsigned short As[64][72];
    __shared__ unsigned short Bs[64][72];
    int tid = threadIdx.x;
    int lane = tid & 63, wave = tid >> 6;
    int m16 = lane & 15, g = lane >> 4, g8 = g * 8;
    int row0 = blockIdx.y * 64, col0 = blockIdx.x * 64;
    int r = tid >> 2, ch = (tid & 3) * 16;

    floatx4 acc[4];
    #pragma unroll
    for (int t = 0; t < 4; ++t) acc[t] = (floatx4){0.f, 0.f, 0.f, 0.f};

    const unsigned short* abase = A  + (size_t)(row0 + r) * D_ + ch;
    const unsigned short* bbase = BT + (size_t)(col0 + r) * D_ + ch;
    uint4 a0 = *reinterpret_cast<const uint4*>(abase);
    uint4 a1 = *reinterpret_cast<const uint4*>(abase + 8);
    uint4 b0 = *reinterpret_cast<const uint4*>(bbase);
    uint4 b1 = *reinterpret_cast<const uint4*>(bbase + 8);

    for (int kc = 0; kc < 16; ++kc) {
        if (kc) {   // prev iteration's LDS reads complete
            asm volatile("s_waitcnt lgkmcnt(0)" ::: "memory");
            __builtin_amdgcn_s_barrier();
        }
        *reinterpret_cast<uint4*>(&As[r][ch])     = a0;
        *reinterpret_cast<uint4*>(&As[r][ch + 8]) = a1;
        *reinterpret_cast<uint4*>(&Bs[r][ch])     = b0;
        *reinterpret_cast<uint4*>(&Bs[r][ch + 8]) = b1;
        if (kc < 15) {   // prefetch next tile; stays in flight across barrier
            int k0 = (kc + 1) * 64;
            a0 = *reinterpret_cast<const uint4*>(abase + k0);
            a1 = *reinterpret_cast<const uint4*>(abase + k0 + 8);
            b0 = *reinterpret_cast<const uint4*>(bbase + k0);
            b1 = *reinterpret_cast<const uint4*>(bbase + k0 + 8);
        }
        asm volatile("s_waitcnt lgkmcnt(0)" ::: "memory");
        __builtin_amdgcn_s_barrier();
        bf16x8 fa0 = as_bf16x8(*reinterpret_cast<ushort8v*>(&As[16 * wave + m16][g8]));
        bf16x8 fa1 = as_bf16x8(*reinterpret_cast<ushort8v*>(&As[16 * wave + m16][32 + g8]));
        #pragma unroll
        for (int t = 0; t < 4; ++t) {
            bf16x8 fb0 = as_bf16x8(*reinterpret_cast<ushort8v*>(&Bs[16 * t + m16][g8]));
            bf16x8 fb1 = as_bf16x8(*reinterpret_cast<ushort8v*>(&Bs[16 * t + m16][32 + g8]));
            acc[t] = __builtin_amdgcn_mfma_f32_16x16x32_bf16(fa0, fb0, acc[t], 0, 0, 0);
            acc[t] = __builtin_amdgcn_mfma_f32_16x16x32_bf16(fa1, fb1, acc[t], 0, 0, 0);
        }
    }
    #pragma unroll
    for (int t = 0; t < 4; ++t)
        #pragma unroll
        for (int reg = 0; reg < 4; ++reg)
            Cb[(size_t)(row0 + 16 * wave + g * 4 + reg) * D_ + col0 + 16 * t + m16] = f2bf(acc[t][reg]);
}

// ---------------- MFMA GEMM (o-proj, fused combine): out = (gacc/l) @ Wo ----------------
__global__ __launch_bounds__(256)
void gemm_attn_kernel(const float* __restrict__ gacc, const float* __restrict__ gacc_l,
                      const unsigned short* __restrict__ BT, float* __restrict__ out) {
    __shared__ unsigned short As[64][72];
    __shared__ unsigned short Bs[64][72];
    int tid = threadIdx.x;
    int lane = tid & 63, wave = tid >> 6;
    int m16 = lane & 15, g = lane >> 4, g8 = g * 8;
    int row0 = blockIdx.y * 64, col0 = blockIdx.x * 64;
    int r = tid >> 2, ch = (tid & 3) * 16;
    int row = row0 + r;

    floatx4 acc[4];
    #pragma unroll
    for (int t = 0; t < 4; ++t) acc[t] = (floatx4){0.f, 0.f, 0.f, 0.f};

    const float* abase = gacc + (size_t)row * D_ + ch;
    const unsigned short* bbase = BT + (size_t)(col0 + r) * D_ + ch;
    float4 av4[4];
    uint4 b0, b1;
    float inv = 1.0f / fmaxf(gacc_l[(size_t)row * H_ + 0], 1e-35f);
    #pragma unroll
    for (int t = 0; t < 4; ++t) av4[t] = reinterpret_cast<const float4*>(abase)[t];
    b0 = *reinterpret_cast<const uint4*>(bbase);
    b1 = *reinterpret_cast<const uint4*>(bbase + 8);

    for (int kc = 0; kc < 16; ++kc) {
        if (kc) {
            asm volatile("s_waitcnt lgkmcnt(0)" ::: "memory");
            __builtin_amdgcn_s_barrier();
        }
        unsigned short av[16];
        #pragma unroll
        for (int t = 0; t < 4; ++t) {
            av[t*4+0] = f2bf(av4[t].x * inv); av[t*4+1] = f2bf(av4[t].y * inv);
            av[t*4+2] = f2bf(av4[t].z * inv); av[t*4+3] = f2bf(av4[t].w * inv);
        }
        *reinterpret_cast<uint4*>(&As[r][ch])     = *reinterpret_cast<uint4*>(&av[0]);
        *reinterpret_cast<uint4*>(&As[r][ch + 8]) = *reinterpret_cast<uint4*>(&av[8]);
        *reinterpret_cast<uint4*>(&Bs[r][ch])     = b0;
        *reinterpret_cast<uint4*>(&Bs[r][ch + 8]) = b1;
        if (kc < 15) {   // prefetch next tile (A, B, and next inv)
            int k0 = (kc + 1) * 64;
            inv = 1.0f / fmaxf(gacc_l[(size_t)row * H_ + kc + 1], 1e-35f);
            #pragma unroll
            for (int t = 0; t < 4; ++t) av4[t] = reinterpret_cast<const float4*>(abase + k0)[t];
            b0 = *reinterpret_cast<const uint4*>(bbase + k0);
            b1 = *reinterpret_cast<const uint4*>(bbase + k0 + 8);
        }
        asm volatile("s_waitcnt lgkmcnt(0)" ::: "memory");
        __builtin_amdgcn_s_barrier();
        bf16x8 fa0 = as_bf16x8(*reinterpret_cast<ushort8v*>(&As[16 * wave + m16][g8]));
        bf16x8 fa1 = as_bf16x8(*reinterpret_cast<ushort8v*>(&As[16 * wave + m16][32 + g8]));
        #pragma unroll
        for (int t = 0; t < 4; ++t) {
            bf16x8 fb0 = as_bf16x8(*reinterpret_cast<ushort8v*>(&Bs[16 * t + m16][g8]));
            bf16x8 fb1 = as_bf16x8(*reinterpret_cast<ushort8v*>(&Bs[16 * t + m16][32 + g8]));
            acc[t] = __builtin_amdgcn_mfma_f32_16x16x32_bf16(fa0, fb0, acc[t], 0, 0, 0);
            acc[t] = __builtin_amdgcn_mfma_f32_16x16x32_bf16(fa1, fb1, acc[t], 0, 0, 0);
        }
    }
    #pragma unroll
    for (int t = 0; t < 4; ++t)
        #pragma unroll
        for (int reg = 0; reg < 4; ++reg)
            out[(size_t)(row0 + 16 * wave + g * 4 + reg) * D_ + col0 + 16 * t + m16] = acc[t][reg];
}

// ---------------- MFMA flash attention, split-K x8, 2 q-strips/block, atomics ----------------
// R14: amortize fixed per-iteration cost (2 barriers + lgkm drains + Ps round-trip)
// over 2x compute: each block owns 128 q-rows (two 64-row strips sharing one staged
// K-tile). NSPLIT 4->8 keeps grid=1024 (exactly 4 blocks/CU, bh-per-XCD swizzle).
// Iters/block 18->9. LDS 34.8KB (Ps->[128][64]) still 4 blocks/CU. setprio REMOVED
// (R13 measured -3.4% on this lockstep-wave structure, consistent with m190).
__global__ __launch_bounds__(256, 4)
void attn_kernel(const unsigned short* __restrict__ qbf,
                 const unsigned short* __restrict__ cbf,
                 const unsigned* __restrict__ maskbits,
                 float* __restrict__ gacc, float* __restrict__ gacc_l) {
    int blk   = blockIdx.x;
    int bh    = ((blk >> 8) << 3) | (blk & 7);   // XCD swizzle: one (b,h) per XCD group
    int inner = (blk >> 3) & 31;
    int qt2   = inner & 3;            // 0..3 : 128-row q-block
    int split = inner >> 2;           // 0..7
    int h  = bh & 15;
    int b  = bh >> 4;
    int tid  = threadIdx.x;
    int lane = tid & 63;
    int wave = tid >> 6;
    int m16  = lane & 15;
    int g    = lane >> 4;
    int g8   = g * 8;

    __shared__ unsigned short Ks [64][72];
    __shared__ unsigned short Kts[64][72];
    __shared__ unsigned short Ps [128][64];

    // Q fragments for both strips (s=0,1 -> rows qt2*128 + s*64 + 16w + m16)
    bf16x8 qa[2][2];
    #pragma unroll
    for (int s = 0; s < 2; ++s) {
        const unsigned short* qrow = qbf
            + ((size_t)(b * NX_ + qt2 * 128 + s * 64 + 16 * wave + m16)) * D_ + h * HD_;
        qa[s][0] = as_bf16x8(*reinterpret_cast<const ushort8v*>(qrow + g8));
        qa[s][1] = as_bf16x8(*reinterpret_cast<const ushort8v*>(qrow + 32 + g8));
    }

    floatx4 acc_o[2][4];
    floatx4 acc_l[2];
    #pragma unroll
    for (int s = 0; s < 2; ++s) {
        #pragma unroll
        for (int td = 0; td < 4; ++td) acc_o[s][td] = (floatx4){0.f, 0.f, 0.f, 0.f};
        acc_l[s] = (floatx4){0.f, 0.f, 0.f, 0.f};
    }

    ushort8v ones_u;
    #pragma unroll
    for (int j = 0; j < 8; ++j) ones_u[j] = 0x3F80;   // bf16 1.0
    bf16x8 onesf = as_bf16x8(ones_u);

    // staging mapping: thread = (Kg, Dg): keys 4Kg..4Kg+3, dims 4Dg..4Dg+3
    int Kg = tid >> 4;          // 0..15
    int Dg = tid & 15;          // 0..15
    int pcst = ((Kg >> 1) + (Dg >> 1)) & 7;   // Kts chunk rotation (uniform per thread)
    int prsw = 2 * ((m16 >> 2) & 3);          // Ps read-side rotation

    int kb0 = split * KBS;

    // ---- prologue: prefetch first K-tile into registers ----
    uint2 rows[4];
    {
        const unsigned short* s0 = (kb0 < 8)
            ? qbf + ((size_t)(b * NX_ + kb0 * 64 + 4 * Kg)) * D_ + h * HD_ + 4 * Dg
            : cbf + ((size_t)(b * NC_ + kb0 * 64 - NX_ + 4 * Kg)) * D_ + h * HD_ + 4 * Dg;
        #pragma unroll
        for (int kk = 0; kk < 4; ++kk)
            rows[kk] = *reinterpret_cast<const uint2*>(s0 + (size_t)kk * D_);
    }

    for (int i = 0; i < KBS; ++i) {
        int kb = kb0 + i;
        // prev iteration's LDS reads complete everywhere; no vmcnt drain (prefetch in flight)
        asm volatile("s_waitcnt lgkmcnt(0)" ::: "memory");
        __builtin_amdgcn_s_barrier();

        // ---- mask loads for both strips, issued early (latency covered by stage+QK) ----
        unsigned mw0[2][4], mw1[2][4];
        if (kb >= 8) {
            #pragma unroll
            for (int s = 0; s < 2; ++s)
                #pragma unroll
                for (int r = 0; r < 4; ++r) {
                    size_t mi = ((size_t)(b * NX_ + qt2 * 128 + s * 64 + 16 * wave + g * 4 + r))
                                * (NC_ / 32) + (size_t)(kb - 8) * 2;
                    uint2 w = *reinterpret_cast<const uint2*>(&maskbits[mi]);
                    mw0[s][r] = w.x; mw1[s][r] = w.y;
                }
        }

        // ---- stage K tile from prefetched regs: 4 b64 Ks writes, reg transpose, 4 b64 Kts ----
        #pragma unroll
        for (int kk = 0; kk < 4; ++kk)
            *reinterpret_cast<uint2*>(&Ks[4 * Kg + kk][4 * Dg]) = rows[kk];
        #pragma unroll
        for (int i2 = 0; i2 < 4; ++i2) {
            unsigned sel = (i2 & 1) ? 0x07060302u : 0x05040100u;
            unsigned r0 = (i2 >> 1) ? rows[0].y : rows[0].x;
            unsigned r1 = (i2 >> 1) ? rows[1].y : rows[1].x;
            unsigned r2 = (i2 >> 1) ? rows[2].y : rows[2].x;
            unsigned r3 = (i2 >> 1) ? rows[3].y : rows[3].x;
            uint2 cw;
            cw.x = __builtin_amdgcn_perm(r1, r0, sel);   // (k0.d, k1.d)
            cw.y = __builtin_amdgcn_perm(r3, r2, sel);   // (k2.d, k3.d)
            *reinterpret_cast<uint2*>(&Kts[4 * Dg + i2][pcst * 8 + 4 * (Kg & 1)]) = cw;
        }

        // ---- prefetch next K-tile into rows (stays in flight across raw barrier) ----
        {
            int kbn = (i + 1 < KBS) ? kb + 1 : kb;
            const unsigned short* sn = (kbn < 8)
                ? qbf + ((size_t)(b * NX_ + kbn * 64 + 4 * Kg)) * D_ + h * HD_ + 4 * Dg
                : cbf + ((size_t)(b * NC_ + kbn * 64 - NX_ + 4 * Kg)) * D_ + h * HD_ + 4 * Dg;
            #pragma unroll
            for (int kk = 0; kk < 4; ++kk)
                rows[kk] = *reinterpret_cast<const uint2*>(sn + (size_t)kk * D_);
        }

        // staging barrier: wait only LDS writes; do NOT drain vmcnt (prefetch in flight)
        asm volatile("s_waitcnt lgkmcnt(0)" ::: "memory");
        __builtin_amdgcn_s_barrier();
        __builtin_amdgcn_sched_barrier(0);
        asm volatile("" ::: "memory");

        const float C1 = 0.18033688011112042f;   // 0.125 * log2(e)
        const float C2 = 92.33248261689366f;

        #pragma unroll
        for (int s = 0; s < 2; ++s) {
            // ---- S = Q @ K^T (strip s) ----
            floatx4 accs[4];
            #pragma unroll
            for (int t = 0; t < 4; ++t) {
                bf16x8 b0 = as_bf16x8(*reinterpret_cast<ushort8v*>(&Ks[16 * t + m16][g8]));
                bf16x8 b1 = as_bf16x8(*reinterpret_cast<ushort8v*>(&Ks[16 * t + m16][32 + g8]));
                floatx4 d = (floatx4){0.f, 0.f, 0.f, 0.f};
                d = __builtin_amdgcn_mfma_f32_16x16x32_bf16(qa[s][0], b0, d, 0, 0, 0);
                d = __builtin_amdgcn_mfma_f32_16x16x32_bf16(qa[s][1], b1, d, 0, 0, 0);
                accs[t] = d;
            }

            // ---- p = exp2(min(fma(s,C1,-C2),0)), masked -> 0; rotated Ps store ----
            #pragma unroll
            for (int t = 0; t < 4; ++t) {
                int cc = 2 * t + (m16 >> 3);
                #pragma unroll
                for (int r = 0; r < 4; ++r) {
                    float e = fminf(fmaf(accs[t][r], C1, -C2), 0.0f);
                    float p = __builtin_amdgcn_exp2f(e);
                    if (kb >= 8) {
                        unsigned w = (t < 2) ? mw0[s][r] : mw1[s][r];
                        unsigned bit = (w >> ((16 * t + m16) & 31)) & 1u;
                        p = bit ? p : 0.0f;
                    }
                    int prow = 64 * s + 16 * wave + g * 4 + r;
                    int pc = (cc + 2 * g) & 7;
                    Ps[prow][pc * 8 + (m16 & 7)] = (unsigned short)(__float_as_uint(p) >> 16);
                }
            }
            asm volatile("s_waitcnt lgkmcnt(0)" ::: "memory");   // own-strip Ps round-trip

            // ---- O += P @ V ; l += P @ ones (MFMA row-sum) ----
            bf16x8 p0 = as_bf16x8(*reinterpret_cast<ushort8v*>(
                &Ps[64 * s + 16 * wave + m16][((g + prsw) & 7) * 8]));
            bf16x8 p1 = as_bf16x8(*reinterpret_cast<ushort8v*>(
                &Ps[64 * s + 16 * wave + m16][((4 + g + prsw) & 7) * 8]));
            acc_l[s] = __builtin_amdgcn_mfma_f32_16x16x32_bf16(p0, onesf, acc_l[s], 0, 0, 0);
            acc_l[s] = __builtin_amdgcn_mfma_f32_16x16x32_bf16(p1, onesf, acc_l[s], 0, 0, 0);
            #pragma unroll
            for (int td = 0; td < 4; ++td) {
                int row = 16 * td + m16;
                int rh = row >> 3;
                bf16x8 v0 = as_bf16x8(*reinterpret_cast<ushort8v*>(&Kts[row][((g + rh) & 7) * 8]));
                bf16x8 v1 = as_bf16x8(*reinterpret_cast<ushort8v*>(&Kts[row][((4 + g + rh) & 7) * 8]));
                acc_o[s][td] = __builtin_amdgcn_mfma_f32_16x16x32_bf16(p0, v0, acc_o[s][td], 0, 0, 0);
                acc_o[s][td] = __builtin_amdgcn_mfma_f32_16x16x32_bf16(p1, v1, acc_o[s][td], 0, 0, 0);
            }
        }
    }

    // ---- epilogue: atomically accumulate partial O and l (both strips) ----
    #pragma unroll
    for (int s = 0; s < 2; ++s)
        #pragma unroll
        for (int r = 0; r < 4; ++r) {
            int qrow_ = qt2 * 128 + s * 64 + 16 * wave + g * 4 + r;
            float* dst = gacc + ((size_t)(b * NX_ + qrow_)) * D_ + h * HD_;
            #pragma unroll
            for (int td = 0; td < 4; ++td)
                unsafeAtomicAdd(&dst[16 * td + m16], acc_o[s][td][r]);
            if (m16 == 0)
                unsafeAtomicAdd(&gacc_l[(size_t)(b * NX_ + qrow_) * H_ + h], acc_l[s][r]);
        }
}

extern "C" void kernel_launch(void* const* d_in, const int* in_sizes, int n_in,
                              void* d_out, int out_size, void* d_ws, size_t ws_size,
                              hipStream_t stream) {
    (void)in_sizes; (void)n_in; (void)out_size;
    const float* x    = (const float*)d_in[0];
    const float* c    = (const float*)d_in[1];
    const int*   mask = (const int*)d_in[2];
    const float* ln_w = (const float*)d_in[3];
    const float* ln_b = (const float*)d_in[4];
    const float* Wq   = (const float*)d_in[5];
    const float* Wo   = (const float*)d_in[6];
    float* out  = (float*)d_out;                    // o: 1,048,576 fp32 (4 MB)
    float* out2 = out + (size_t)B_ * NX_ * D_;      // kv0: 8,388,608 fp32 (32 MB)

    // scratch: prefer d_ws (traffic-neutral per R10/R11 comparison); with ws, kv0 is
    // fused into prep (saves a 32MB re-read + one launch). Fallback: carve out2.
    const size_t SCRATCH_FLOATS = 8011776;
    bool use_ws = (d_ws != nullptr) && (ws_size >= SCRATCH_FLOATS * sizeof(float));
    float* base = use_ws ? (float*)d_ws : out2;

    unsigned short* qbf      = (unsigned short*)(base);               // [0,       524288)
    unsigned*       maskbits = (unsigned*)(base + 524288);            // [524288,  655360)
    float*          gacc     = base + 655360;                         // [655360,  1703936)
    float*          gacc_l   = base + 1703936;                        // [1703936, 1720320)
    unsigned short* WqT      = (unsigned short*)(base + 1720320);     // [1720320, 2244608)
    unsigned short* WoT      = (unsigned short*)(base + 2244608);     // [2244608, 2768896)
    unsigned short* xnb      = (unsigned short*)(base + 2768896);     // [2768896, 3293184)
    unsigned short* cbf      = (unsigned short*)(base + 3817472);     // [3817472, 8011776)

    prep_kernel<<<11280, 256, 0, stream>>>(x, ln_w, ln_b, Wq, Wo, mask, c,
                                           xnb, WqT, WoT, maskbits, cbf, gacc,
                                           use_ws ? out2 : nullptr);
    gemm_bt_kernel<<<dim3(16, 16), 256, 0, stream>>>(xnb, WqT, qbf);
    attn_kernel<<<1024, 256, 0, stream>>>(qbf, cbf, maskbits, gacc, gacc_l);
    gemm_attn_kernel<<<dim3(16, 16), 256, 0, stream>>>(gacc, gacc_l, WoT, out);
    if (!use_ws)
        kv0_kernel<<<(B_ * H_ * NC_ * HD_ / 4) / 256, 256, 0, stream>>>(c, out2);
}

// Round 6
// 179.933 us; speedup vs baseline: 1.1726x; 1.1726x over previous
//
#include <hip/hip_runtime.h>

#define B_  2
#define NX_ 512
#define NC_ 4096
#define D_  1024
#define H_  16
#define HD_ 64
#define NT_ (NX_ + NC_)   // 4608
#define NSPLIT 4
#define KBS (NT_ / 64 / NSPLIT)   // 18 key-blocks per split

typedef float  floatx4  __attribute__((ext_vector_type(4)));
typedef __bf16 bf16x8   __attribute__((ext_vector_type(8)));
typedef unsigned short ushort8v __attribute__((ext_vector_type(8)));

__device__ __forceinline__ bf16x8 as_bf16x8(ushort8v u) {
    union { ushort8v u; bf16x8 b; } c; c.u = u; return c.b;
}
// fp32 -> bf16 round-to-nearest-even
__device__ __forceinline__ unsigned short f2bf(float f) {
    unsigned u = __float_as_uint(f);
    u += 0x7FFF + ((u >> 16) & 1);
    return (unsigned short)(u >> 16);
}

// ================ prep: LN + tcast(Wq) + tcast(Wo) + pack_mask + cast(c) [+ fused kv0] + zero(gacc) ================
__global__ __launch_bounds__(256)
void prep_kernel(const float* __restrict__ x, const float* __restrict__ lw,
                 const float* __restrict__ lb, const float* __restrict__ Wq,
                 const float* __restrict__ Wo, const int* __restrict__ mask,
                 const float* __restrict__ c,
                 unsigned short* __restrict__ xnb, unsigned short* __restrict__ WqT,
                 unsigned short* __restrict__ WoT, unsigned* __restrict__ bits,
                 unsigned short* __restrict__ cbf, float* __restrict__ gz,
                 float* __restrict__ kv0o) {
    int blk = blockIdx.x;
    int tid = threadIdx.x;
    if (blk < 1024) {
        int row = blk;
        float4 v = reinterpret_cast<const float4*>(x)[(size_t)row * (D_ / 4) + tid];
        float s  = v.x + v.y + v.z + v.w;
        float s2 = v.x * v.x + v.y * v.y + v.z * v.z + v.w * v.w;
        #pragma unroll
        for (int off = 32; off > 0; off >>= 1) {
            s  += __shfl_down(s, off);
            s2 += __shfl_down(s2, off);
        }
        __shared__ float sm[4], sm2[4], stat[2];
        int wv = tid >> 6;
        if ((tid & 63) == 0) { sm[wv] = s; sm2[wv] = s2; }
        __syncthreads();
        if (tid == 0) {
            float S  = sm[0] + sm[1] + sm[2] + sm[3];
            float S2 = sm2[0] + sm2[1] + sm2[2] + sm2[3];
            float mu  = S * (1.0f / D_);
            float var = fmaxf(S2 * (1.0f / D_) - mu * mu, 0.0f);
            stat[0] = mu;
            stat[1] = rsqrtf(var + 1e-5f);
        }
        __syncthreads();
        float mu = stat[0], rs = stat[1];
        float4 w4 = reinterpret_cast<const float4*>(lw)[tid];
        float4 b4 = reinterpret_cast<const float4*>(lb)[tid];
        ushort4 o;
        o.x = f2bf((v.x - mu) * rs * w4.x + b4.x);
        o.y = f2bf((v.y - mu) * rs * w4.y + b4.y);
        o.z = f2bf((v.z - mu) * rs * w4.z + b4.z);
        o.w = f2bf((v.w - mu) * rs * w4.w + b4.w);
        reinterpret_cast<ushort4*>(xnb)[(size_t)row * (D_ / 4) + tid] = o;
    } else if (blk < 1536) {
        int which = (blk - 1024) >> 8;
        int t = (blk - 1024) & 255;
        const float* W = which ? Wo : Wq;
        unsigned short* WT = which ? WoT : WqT;
        __shared__ unsigned short T[64][72];
        int row0 = (t >> 4) * 64, col0 = (t & 15) * 64;
        int r = tid >> 2, ch = (tid & 3) * 16;
        const float* src = W + (size_t)(row0 + r) * D_ + col0 + ch;
        unsigned short vals[16];
        #pragma unroll
        for (int k = 0; k < 4; ++k) {
            float4 v = reinterpret_cast<const float4*>(src)[k];
            vals[k*4+0] = f2bf(v.x); vals[k*4+1] = f2bf(v.y);
            vals[k*4+2] = f2bf(v.z); vals[k*4+3] = f2bf(v.w);
        }
        #pragma unroll
        for (int i = 0; i < 16; ++i) T[ch + i][r] = vals[i];
        __syncthreads();
        unsigned short* dst = WT + (size_t)(col0 + r) * D_ + row0 + ch;
        uint4 o0 = *reinterpret_cast<uint4*>(&T[r][ch]);
        uint4 o1 = *reinterpret_cast<uint4*>(&T[r][ch + 8]);
        *reinterpret_cast<uint4*>(dst)     = o0;
        *reinterpret_cast<uint4*>(dst + 8) = o1;
    } else if (blk < 2048) {
        size_t w = (size_t)(blk - 1536) * 256 + tid;
        const int* src = mask + w * 32;
        unsigned b = 0;
        #pragma unroll
        for (int k = 0; k < 8; ++k) {
            int4 v = reinterpret_cast<const int4*>(src)[k];
            b |= (v.x != 0 ? 1u : 0u) << (k * 4 + 0);
            b |= (v.y != 0 ? 1u : 0u) << (k * 4 + 1);
            b |= (v.z != 0 ? 1u : 0u) << (k * 4 + 2);
            b |= (v.w != 0 ? 1u : 0u) << (k * 4 + 3);
        }
        bits[w] = b;
    } else if (blk < 10240) {
        size_t i = ((size_t)(blk - 2048) * 256 + tid) * 4;
        float4 v = *reinterpret_cast<const float4*>(c + i);
        ushort4 o;
        o.x = f2bf(v.x); o.y = f2bf(v.y); o.z = f2bf(v.z); o.w = f2bf(v.w);
        *reinterpret_cast<ushort4*>(cbf + i) = o;
        if (kv0o != nullptr) {
            // fused kv0: out2[b,h,n,d] = c[b,n,h*64+d]
            size_t row = i >> 10;            // b*NC_ + n
            int dd = (int)(i & 1023);
            int hh = dd >> 6, d4 = (dd & 63) >> 2;
            int bb = (int)(row >> 12);       // /NC_
            int n  = (int)(row & 4095);
            size_t o4 = (((size_t)(bb * 16 + hh) * NC_ + n) << 4) + d4;  // float4 index
            reinterpret_cast<float4*>(kv0o)[o4] = v;
        }
    } else {
        size_t i = ((size_t)(blk - 10240) * 256 + tid) * 4;
        float4 z = {0.f, 0.f, 0.f, 0.f};
        *reinterpret_cast<float4*>(gz + i) = z;
    }
}

// ---------------- kv0 fallback (only when d_ws too small): runs LAST ----------------
__global__ __launch_bounds__(256)
void kv0_kernel(const float* __restrict__ c, float* __restrict__ out2) {
    size_t i = (size_t)blockIdx.x * 256 + threadIdx.x;
    int d4 = (int)(i & 15);
    size_t r = i >> 4;
    int n = (int)(r % NC_);
    size_t r2 = r / NC_;
    int h = (int)(r2 & (H_ - 1));
    int b = (int)(r2 >> 4);
    float4 v = *reinterpret_cast<const float4*>(c + ((size_t)(b * NC_ + n)) * D_ + h * HD_ + d4 * 4);
    reinterpret_cast<float4*>(out2)[i] = v;
}

// ---------------- MFMA GEMM (q-proj): qbf = xnb @ Wq (B given as WqT); out bf16 ----------------
// R15: 64x32 tiles -> 512 blocks = 2 blocks/CU (was 64x64, 256 blocks, 1/CU
// lockstep). Inter-block overlap hides the per-iter barrier/staging chain — the
// same mechanism as attn's 4 blocks/CU. A/B working set ~4MB, L2-resident.
__global__ __launch_bounds__(256)
void gemm_bt_kernel(const unsigned short* __restrict__ A, const unsigned short* __restrict__ BT,
                    unsigned short* __restrict__ Cb) {
    __shared__ unsigned short As[64][72];
    __shared__ unsigned short Bs[32][72];
    int tid = threadIdx.x;
    int lane = tid & 63, wave = tid >> 6;
    int m16 = lane & 15, g = lane >> 4, g8 = g * 8;
    int row0 = blockIdx.y * 64, col0 = blockIdx.x * 32;
    int r = tid >> 2, ch = (tid & 3) * 16;
    int rB = tid >> 3, chB = (tid & 7) * 8;

    floatx4 acc[2];
    #pragma unroll
    for (int t = 0; t < 2; ++t) acc[t] = (floatx4){0.f, 0.f, 0.f, 0.f};

    const unsigned short* abase = A  + (size_t)(row0 + r) * D_ + ch;
    const unsigned short* bbase = BT + (size_t)(col0 + rB) * D_ + chB;
    uint4 a0 = *reinterpret_cast<const uint4*>(abase);
    uint4 a1 = *reinterpret_cast<const uint4*>(abase + 8);
    uint4 b0 = *reinterpret_cast<const uint4*>(bbase);

    for (int kc = 0; kc < 16; ++kc) {
        if (kc) {   // prev iteration's LDS reads complete
            asm volatile("s_waitcnt lgkmcnt(0)" ::: "memory");
            __builtin_amdgcn_s_barrier();
        }
        *reinterpret_cast<uint4*>(&As[r][ch])     = a0;
        *reinterpret_cast<uint4*>(&As[r][ch + 8]) = a1;
        *reinterpret_cast<uint4*>(&Bs[rB][chB])   = b0;
        if (kc < 15) {   // prefetch next tile; stays in flight across barrier
            int k0 = (kc + 1) * 64;
            a0 = *reinterpret_cast<const uint4*>(abase + k0);
            a1 = *reinterpret_cast<const uint4*>(abase + k0 + 8);
            b0 = *reinterpret_cast<const uint4*>(bbase + k0);
        }
        asm volatile("s_waitcnt lgkmcnt(0)" ::: "memory");
        __builtin_amdgcn_s_barrier();
        bf16x8 fa0 = as_bf16x8(*reinterpret_cast<ushort8v*>(&As[16 * wave + m16][g8]));
        bf16x8 fa1 = as_bf16x8(*reinterpret_cast<ushort8v*>(&As[16 * wave + m16][32 + g8]));
        #pragma unroll
        for (int t = 0; t < 2; ++t) {
            bf16x8 fb0 = as_bf16x8(*reinterpret_cast<ushort8v*>(&Bs[16 * t + m16][g8]));
            bf16x8 fb1 = as_bf16x8(*reinterpret_cast<ushort8v*>(&Bs[16 * t + m16][32 + g8]));
            acc[t] = __builtin_amdgcn_mfma_f32_16x16x32_bf16(fa0, fb0, acc[t], 0, 0, 0);
            acc[t] = __builtin_amdgcn_mfma_f32_16x16x32_bf16(fa1, fb1, acc[t], 0, 0, 0);
        }
    }
    #pragma unroll
    for (int t = 0; t < 2; ++t)
        #pragma unroll
        for (int reg = 0; reg < 4; ++reg)
            Cb[(size_t)(row0 + 16 * wave + g * 4 + reg) * D_ + col0 + 16 * t + m16] = f2bf(acc[t][reg]);
}

// ---------------- MFMA GEMM (o-proj, fused combine): out = (gacc/l) @ Wo ----------------
__global__ __launch_bounds__(256)
void gemm_attn_kernel(const float* __restrict__ gacc, const float* __restrict__ gacc_l,
                      const unsigned short* __restrict__ BT, float* __restrict__ out) {
    __shared__ unsigned short As[64][72];
    __shared__ unsigned short Bs[32][72];
    int tid = threadIdx.x;
    int lane = tid & 63, wave = tid >> 6;
    int m16 = lane & 15, g = lane >> 4, g8 = g * 8;
    int row0 = blockIdx.y * 64, col0 = blockIdx.x * 32;
    int r = tid >> 2, ch = (tid & 3) * 16;
    int rB = tid >> 3, chB = (tid & 7) * 8;
    int row = row0 + r;

    floatx4 acc[2];
    #pragma unroll
    for (int t = 0; t < 2; ++t) acc[t] = (floatx4){0.f, 0.f, 0.f, 0.f};

    const float* abase = gacc + (size_t)row * D_ + ch;
    const unsigned short* bbase = BT + (size_t)(col0 + rB) * D_ + chB;
    float4 av4[4];
    uint4 b0;
    float inv = 1.0f / fmaxf(gacc_l[(size_t)row * H_ + 0], 1e-35f);
    #pragma unroll
    for (int t = 0; t < 4; ++t) av4[t] = reinterpret_cast<const float4*>(abase)[t];
    b0 = *reinterpret_cast<const uint4*>(bbase);

    for (int kc = 0; kc < 16; ++kc) {
        if (kc) {
            asm volatile("s_waitcnt lgkmcnt(0)" ::: "memory");
            __builtin_amdgcn_s_barrier();
        }
        unsigned short av[16];
        #pragma unroll
        for (int t = 0; t < 4; ++t) {
            av[t*4+0] = f2bf(av4[t].x * inv); av[t*4+1] = f2bf(av4[t].y * inv);
            av[t*4+2] = f2bf(av4[t].z * inv); av[t*4+3] = f2bf(av4[t].w * inv);
        }
        *reinterpret_cast<uint4*>(&As[r][ch])     = *reinterpret_cast<uint4*>(&av[0]);
        *reinterpret_cast<uint4*>(&As[r][ch + 8]) = *reinterpret_cast<uint4*>(&av[8]);
        *reinterpret_cast<uint4*>(&Bs[rB][chB])   = b0;
        if (kc < 15) {   // prefetch next tile (A, B, and next inv)
            int k0 = (kc + 1) * 64;
            inv = 1.0f / fmaxf(gacc_l[(size_t)row * H_ + kc + 1], 1e-35f);
            #pragma unroll
            for (int t = 0; t < 4; ++t) av4[t] = reinterpret_cast<const float4*>(abase + k0)[t];
            b0 = *reinterpret_cast<const uint4*>(bbase + k0);
        }
        asm volatile("s_waitcnt lgkmcnt(0)" ::: "memory");
        __builtin_amdgcn_s_barrier();
        bf16x8 fa0 = as_bf16x8(*reinterpret_cast<ushort8v*>(&As[16 * wave + m16][g8]));
        bf16x8 fa1 = as_bf16x8(*reinterpret_cast<ushort8v*>(&As[16 * wave + m16][32 + g8]));
        #pragma unroll
        for (int t = 0; t < 2; ++t) {
            bf16x8 fb0 = as_bf16x8(*reinterpret_cast<ushort8v*>(&Bs[16 * t + m16][g8]));
            bf16x8 fb1 = as_bf16x8(*reinterpret_cast<ushort8v*>(&Bs[16 * t + m16][32 + g8]));
            acc[t] = __builtin_amdgcn_mfma_f32_16x16x32_bf16(fa0, fb0, acc[t], 0, 0, 0);
            acc[t] = __builtin_amdgcn_mfma_f32_16x16x32_bf16(fa1, fb1, acc[t], 0, 0, 0);
        }
    }
    #pragma unroll
    for (int t = 0; t < 2; ++t)
        #pragma unroll
        for (int reg = 0; reg < 4; ++reg)
            out[(size_t)(row0 + 16 * wave + g * 4 + reg) * D_ + col0 + 16 * t + m16] = acc[t][reg];
}

// ---------------- MFMA flash attention, split-K x4, atomic accumulation ----------------
// R15: attn restored to R12-exact — the best-measured structure (51.6us):
// NSPLIT=4, one 64-row q-strip, __syncthreads top barrier, NO setprio.
// R13's micro-bundle (lgkm-only top barrier + setprio) was -3.4%; R14's 2-strip
// NSPLIT=8 was -48% (atomic WRITE 18->54MB L2 amplification). Do not re-try
// occupancy/split increases on this kernel: L2 working set is the binding limit.
__global__ __launch_bounds__(256, 4)
void attn_kernel(const unsigned short* __restrict__ qbf,
                 const unsigned short* __restrict__ cbf,
                 const unsigned* __restrict__ maskbits,
                 float* __restrict__ gacc, float* __restrict__ gacc_l) {
    int blk   = blockIdx.x;
    int bh    = ((blk >> 8) << 3) | (blk & 7);   // XCD swizzle: one (b,h) per XCD group
    int inner = (blk >> 3) & 31;
    int qt    = inner & 7;
    int split = inner >> 3;
    int h  = bh & 15;
    int b  = bh >> 4;
    int tid  = threadIdx.x;
    int lane = tid & 63;
    int wave = tid >> 6;
    int m16  = lane & 15;
    int g    = lane >> 4;
    int g8   = g * 8;

    __shared__ unsigned short Ks [64][72];
    __shared__ unsigned short Kts[64][72];
    __shared__ unsigned short Ps [64][64];

    const unsigned short* qrow = qbf + ((size_t)(b * NX_ + qt * 64 + 16 * wave + m16)) * D_ + h * HD_;
    bf16x8 qa0 = as_bf16x8(*reinterpret_cast<const ushort8v*>(qrow + g8));
    bf16x8 qa1 = as_bf16x8(*reinterpret_cast<const ushort8v*>(qrow + 32 + g8));

    floatx4 acc_o[4];
    #pragma unroll
    for (int td = 0; td < 4; ++td) acc_o[td] = (floatx4){0.f, 0.f, 0.f, 0.f};
    floatx4 acc_l = (floatx4){0.f, 0.f, 0.f, 0.f};

    ushort8v ones_u;
    #pragma unroll
    for (int j = 0; j < 8; ++j) ones_u[j] = 0x3F80;   // bf16 1.0
    bf16x8 onesf = as_bf16x8(ones_u);

    // staging mapping: thread = (Kg, Dg): keys 4Kg..4Kg+3, dims 4Dg..4Dg+3
    int Kg = tid >> 4;          // 0..15
    int Dg = tid & 15;          // 0..15
    int pcst = ((Kg >> 1) + (Dg >> 1)) & 7;   // Kts chunk rotation (uniform per thread)
    int prsw = 2 * ((m16 >> 2) & 3);          // Ps read-side rotation

    int kb0 = split * KBS;

    // ---- prologue: prefetch first K-tile into registers ----
    uint2 rows[4];
    {
        const unsigned short* s0 = (kb0 < 8)
            ? qbf + ((size_t)(b * NX_ + kb0 * 64 + 4 * Kg)) * D_ + h * HD_ + 4 * Dg
            : cbf + ((size_t)(b * NC_ + kb0 * 64 - NX_ + 4 * Kg)) * D_ + h * HD_ + 4 * Dg;
        #pragma unroll
        for (int kk = 0; kk < 4; ++kk)
            rows[kk] = *reinterpret_cast<const uint2*>(s0 + (size_t)kk * D_);
    }

    for (int i = 0; i < KBS; ++i) {
        int kb = kb0 + i;
        __syncthreads();   // full fence: prev LDS reads done everywhere; drains prefetch vmcnt

        // ---- mask loads for this kb, issued early (latency covered by stage+QK) ----
        unsigned mw0[4], mw1[4];
        if (kb >= 8) {
            #pragma unroll
            for (int r = 0; r < 4; ++r) {
                size_t mi = ((size_t)(b * NX_ + qt * 64 + 16 * wave + g * 4 + r)) * (NC_ / 32)
                          + (size_t)(kb - 8) * 2;
                uint2 w = *reinterpret_cast<const uint2*>(&maskbits[mi]);
                mw0[r] = w.x; mw1[r] = w.y;
            }
        }

        // ---- stage K tile from prefetched regs: 4 b64 Ks writes, reg transpose, 4 b64 Kts ----
        #pragma unroll
        for (int kk = 0; kk < 4; ++kk)
            *reinterpret_cast<uint2*>(&Ks[4 * Kg + kk][4 * Dg]) = rows[kk];
        #pragma unroll
        for (int i2 = 0; i2 < 4; ++i2) {
            unsigned sel = (i2 & 1) ? 0x07060302u : 0x05040100u;
            unsigned r0 = (i2 >> 1) ? rows[0].y : rows[0].x;
            unsigned r1 = (i2 >> 1) ? rows[1].y : rows[1].x;
            unsigned r2 = (i2 >> 1) ? rows[2].y : rows[2].x;
            unsigned r3 = (i2 >> 1) ? rows[3].y : rows[3].x;
            uint2 cw;
            cw.x = __builtin_amdgcn_perm(r1, r0, sel);   // (k0.d, k1.d)
            cw.y = __builtin_amdgcn_perm(r3, r2, sel);   // (k2.d, k3.d)
            *reinterpret_cast<uint2*>(&Kts[4 * Dg + i2][pcst * 8 + 4 * (Kg & 1)]) = cw;
        }

        // ---- prefetch next K-tile into rows (stays in flight across raw barrier) ----
        {
            int kbn = (i + 1 < KBS) ? kb + 1 : kb;
            const unsigned short* sn = (kbn < 8)
                ? qbf + ((size_t)(b * NX_ + kbn * 64 + 4 * Kg)) * D_ + h * HD_ + 4 * Dg
                : cbf + ((size_t)(b * NC_ + kbn * 64 - NX_ + 4 * Kg)) * D_ + h * HD_ + 4 * Dg;
            #pragma unroll
            for (int kk = 0; kk < 4; ++kk)
                rows[kk] = *reinterpret_cast<const uint2*>(sn + (size_t)kk * D_);
        }

        // staging barrier: wait only LDS writes; do NOT drain vmcnt (prefetch in flight)
        asm volatile("s_waitcnt lgkmcnt(0)" ::: "memory");
        __builtin_amdgcn_s_barrier();
        __builtin_amdgcn_sched_barrier(0);
        asm volatile("" ::: "memory");

        // ---- S = Q @ K^T ----
        floatx4 accs[4];
        #pragma unroll
        for (int t = 0; t < 4; ++t) {
            bf16x8 b0 = as_bf16x8(*reinterpret_cast<ushort8v*>(&Ks[16 * t + m16][g8]));
            bf16x8 b1 = as_bf16x8(*reinterpret_cast<ushort8v*>(&Ks[16 * t + m16][32 + g8]));
            floatx4 d = (floatx4){0.f, 0.f, 0.f, 0.f};
            d = __builtin_amdgcn_mfma_f32_16x16x32_bf16(qa0, b0, d, 0, 0, 0);
            d = __builtin_amdgcn_mfma_f32_16x16x32_bf16(qa1, b1, d, 0, 0, 0);
            accs[t] = d;
        }

        // ---- p = exp2(min(fma(s,C1,-C2),0)), masked -> 0; rotated Ps store (trunc bf16) ----
        const float C1 = 0.18033688011112042f;   // 0.125 * log2(e)
        const float C2 = 92.33248261689366f;
        #pragma unroll
        for (int t = 0; t < 4; ++t) {
            int cc = 2 * t + (m16 >> 3);
            #pragma unroll
            for (int r = 0; r < 4; ++r) {
                float e = fminf(fmaf(accs[t][r], C1, -C2), 0.0f);
                float p = __builtin_amdgcn_exp2f(e);
                if (kb >= 8) {
                    unsigned w = (t < 2) ? mw0[r] : mw1[r];
                    unsigned bit = (w >> ((16 * t + m16) & 31)) & 1u;
                    p = bit ? p : 0.0f;
                }
                int prow = 16 * wave + g * 4 + r;
                int pc = (cc + 2 * g) & 7;
                Ps[prow][pc * 8 + (m16 & 7)] = (unsigned short)(__float_as_uint(p) >> 16);
            }
        }
        asm volatile("s_waitcnt lgkmcnt(0)" ::: "memory");   // own-strip Ps round-trip

        // ---- O += P @ V ; l += P @ ones (MFMA row-sum) ----
        bf16x8 p0 = as_bf16x8(*reinterpret_cast<ushort8v*>(&Ps[16 * wave + m16][((g + prsw) & 7) * 8]));
        bf16x8 p1 = as_bf16x8(*reinterpret_cast<ushort8v*>(&Ps[16 * wave + m16][((4 + g + prsw) & 7) * 8]));
        acc_l = __builtin_amdgcn_mfma_f32_16x16x32_bf16(p0, onesf, acc_l, 0, 0, 0);
        acc_l = __builtin_amdgcn_mfma_f32_16x16x32_bf16(p1, onesf, acc_l, 0, 0, 0);
        #pragma unroll
        for (int td = 0; td < 4; ++td) {
            int row = 16 * td + m16;
            int rh = row >> 3;
            bf16x8 v0 = as_bf16x8(*reinterpret_cast<ushort8v*>(&Kts[row][((g + rh) & 7) * 8]));
            bf16x8 v1 = as_bf16x8(*reinterpret_cast<ushort8v*>(&Kts[row][((4 + g + rh) & 7) * 8]));
            acc_o[td] = __builtin_amdgcn_mfma_f32_16x16x32_bf16(p0, v0, acc_o[td], 0, 0, 0);
            acc_o[td] = __builtin_amdgcn_mfma_f32_16x16x32_bf16(p1, v1, acc_o[td], 0, 0, 0);
        }
    }

    // ---- epilogue: atomically accumulate partial O and l ----
    #pragma unroll
    for (int r = 0; r < 4; ++r) {
        int qrow_ = qt * 64 + 16 * wave + g * 4 + r;
        float* dst = gacc + ((size_t)(b * NX_ + qrow_)) * D_ + h * HD_;
        #pragma unroll
        for (int td = 0; td < 4; ++td)
            unsafeAtomicAdd(&dst[16 * td + m16], acc_o[td][r]);
        if (m16 == 0)
            unsafeAtomicAdd(&gacc_l[(size_t)(b * NX_ + qrow_) * H_ + h], acc_l[r]);
    }
}

extern "C" void kernel_launch(void* const* d_in, const int* in_sizes, int n_in,
                              void* d_out, int out_size, void* d_ws, size_t ws_size,
                              hipStream_t stream) {
    (void)in_sizes; (void)n_in; (void)out_size;
    const float* x    = (const float*)d_in[0];
    const float* c    = (const float*)d_in[1];
    const int*   mask = (const int*)d_in[2];
    const float* ln_w = (const float*)d_in[3];
    const float* ln_b = (const float*)d_in[4];
    const float* Wq   = (const float*)d_in[5];
    const float* Wo   = (const float*)d_in[6];
    float* out  = (float*)d_out;                    // o: 1,048,576 fp32 (4 MB)
    float* out2 = out + (size_t)B_ * NX_ * D_;      // kv0: 8,388,608 fp32 (32 MB)

    // scratch: prefer d_ws (traffic-neutral per R10/R11 comparison); with ws, kv0 is
    // fused into prep (saves a 32MB re-read + one launch). Fallback: carve out2.
    const size_t SCRATCH_FLOATS = 8011776;
    bool use_ws = (d_ws != nullptr) && (ws_size >= SCRATCH_FLOATS * sizeof(float));
    float* base = use_ws ? (float*)d_ws : out2;

    unsigned short* qbf      = (unsigned short*)(base);               // [0,       524288)
    unsigned*       maskbits = (unsigned*)(base + 524288);            // [524288,  655360)
    float*          gacc     = base + 655360;                         // [655360,  1703936)
    float*          gacc_l   = base + 1703936;                        // [1703936, 1720320)
    unsigned short* WqT      = (unsigned short*)(base + 1720320);     // [1720320, 2244608)
    unsigned short* WoT      = (unsigned short*)(base + 2244608);     // [2244608, 2768896)
    unsigned short* xnb      = (unsigned short*)(base + 2768896);     // [2768896, 3293184)
    unsigned short* cbf      = (unsigned short*)(base + 3817472);     // [3817472, 8011776)

    prep_kernel<<<11280, 256, 0, stream>>>(x, ln_w, ln_b, Wq, Wo, mask, c,
                                           xnb, WqT, WoT, maskbits, cbf, gacc,
                                           use_ws ? out2 : nullptr);
    gemm_bt_kernel<<<dim3(32, 16), 256, 0, stream>>>(xnb, WqT, qbf);
    attn_kernel<<<NSPLIT * 256, 256, 0, stream>>>(qbf, cbf, maskbits, gacc, gacc_l);
    gemm_attn_kernel<<<dim3(32, 16), 256, 0, stream>>>(gacc, gacc_l, WoT, out);
    if (!use_ws)
        kv0_kernel<<<(B_ * H_ * NC_ * HD_ / 4) / 256, 256, 0, stream>>>(c, out2);
}